// Round 4
// baseline (16653.217 us; speedup 1.0000x reference)
//
#include <hip/hip_runtime.h>
#include <stdint.h>
#include <math.h>

#define N_TOT 131072   // NSEQ * T
#define TSEQ  2048
#define NSEQ  64
#define CS    128      // chunk steps
#define NCH   16       // chunks
#define PARTS 4        // WGs per sequence

typedef unsigned long long u64;

// ---------------------------------------------------------------------------
// One-time: transpose W_hh (1024x256, row = gate*256+u) into
// Wg[k][u][gate]  (k-major, unit, 4 gates contiguous).
// ---------------------------------------------------------------------------
__global__ __launch_bounds__(256)
void transpose_whh(const float* __restrict__ Whh, float* __restrict__ Wg)
{
    const int k = blockIdx.x;     // 0..255
    const int u = threadIdx.x;    // 0..255
#pragma unroll
    for (int g = 0; g < 4; ++g)
        Wg[(size_t)k * 1024 + u * 4 + g] = Whh[(size_t)(g * 256 + u) * 256 + k];
}

// ---------------------------------------------------------------------------
// gemm_xg (chunk): xg[lr][u*4+g] = feats @ W_ih^T + b_ih + b_hh  (permuted)
// grid (8, 64): bx = n-tile, by = seq. fp32, 128x128 tile, 8x8 reg block.
// ---------------------------------------------------------------------------
__global__ __launch_bounds__(256)
void gemm_xg(const float* __restrict__ A, const float* __restrict__ Wih,
             const float* __restrict__ bih, const float* __restrict__ bhh,
             float* __restrict__ xg, int base)
{
    __shared__ float As[16][136];
    __shared__ float Bs[16][136];
    const int t  = threadIdx.x;
    const int n0 = blockIdx.x * 128;
    const int seq = blockIdx.y;
    const size_t grow0 = (size_t)seq * TSEQ + base;
    const size_t lrow0 = (size_t)seq * CS;
    const int tx = t & 15, ty = t >> 4;

    float acc[8][8];
#pragma unroll
    for (int i = 0; i < 8; ++i)
#pragma unroll
        for (int j = 0; j < 8; ++j) acc[i][j] = 0.f;

    for (int kt = 0; kt < 256; kt += 16) {
#pragma unroll
        for (int jj = 0; jj < 2; ++jj) {
            int idx = t + 256 * jj;
            int m = idx >> 2, q = idx & 3;
            float4 a = *(const float4*)(A + (grow0 + m) * 256 + kt + q * 4);
            As[q * 4 + 0][m] = a.x; As[q * 4 + 1][m] = a.y;
            As[q * 4 + 2][m] = a.z; As[q * 4 + 3][m] = a.w;
            float4 b = *(const float4*)(Wih + (size_t)(n0 + m) * 256 + kt + q * 4);
            Bs[q * 4 + 0][m] = b.x; Bs[q * 4 + 1][m] = b.y;
            Bs[q * 4 + 2][m] = b.z; Bs[q * 4 + 3][m] = b.w;
        }
        __syncthreads();
#pragma unroll
        for (int k = 0; k < 16; ++k) {
            float4 a0 = *(const float4*)&As[k][ty * 8];
            float4 a1 = *(const float4*)&As[k][ty * 8 + 4];
            float4 b0 = *(const float4*)&Bs[k][tx * 8];
            float4 b1 = *(const float4*)&Bs[k][tx * 8 + 4];
            float av[8] = {a0.x, a0.y, a0.z, a0.w, a1.x, a1.y, a1.z, a1.w};
            float bv[8] = {b0.x, b0.y, b0.z, b0.w, b1.x, b1.y, b1.z, b1.w};
#pragma unroll
            for (int i = 0; i < 8; ++i)
#pragma unroll
                for (int j = 0; j < 8; ++j) acc[i][j] += av[i] * bv[j];
        }
        __syncthreads();
    }
#pragma unroll
    for (int i = 0; i < 8; ++i) {
        size_t lr = lrow0 + ty * 8 + i;
#pragma unroll
        for (int j = 0; j < 8; ++j) {
            int n = n0 + tx * 8 + j;      // gate-major index 0..1023
            int gate = n >> 8, u = n & 255;
            xg[lr * 1024 + u * 4 + gate] = acc[i][j] + bih[n] + bhh[n];
        }
    }
}

// ---------------------------------------------------------------------------
// L2-path 8-byte exchange primitives (same-XCD shared L2).
// CDNA vector L1 is write-through, so a plain global store lands in the
// XCD-shared L2; the reader bypasses its own L1 with sc0 and reads that L2.
// ---------------------------------------------------------------------------
__device__ __forceinline__ void l2_store_u64(u64* p, u64 v)
{
    asm volatile("global_store_dwordx2 %0, %1, off"
                 :: "v"(p), "v"(v) : "memory");
}

__device__ __forceinline__ u64 l2_load_u64(const u64* p)
{
    u64 v;
    asm volatile("global_load_dwordx2 %0, %1, off sc0\n\t"
                 "s_waitcnt vmcnt(0)"
                 : "=v"(v) : "v"(p) : "memory");
    return v;
}

// ---------------------------------------------------------------------------
// lstm4: register-resident weights, tagged-word h exchange.
// 256 WGs = 64 seqs x 4 parts (64 units each). Thread (u=t&63, q=t>>6) holds
// W[k in q*16..+16) x 4 gates] = 16 float4 in VGPRs.
//
// blockIdx remap co-locates the 4 parts of each seq on one XCD:
//   bid = (s&7) + 8*(4*(s>>3) + p)
// All four bids share bid%8 AND live in the same aligned 32-block, so both
// round-robin (bid%8) and chunked (bid/32) dispatch policies co-locate them.
//
// h exchange is dual-published per step:
//   hx2 (plain store / sc0 poll)  — fast path through the shared per-XCD L2
//   hx  (AGENT-scope atomics)     — MALL path, always valid
// Readers try the fast path with a bounded probe (768 polls); on timeout
// they set fastState=1 (workspace) and fall back permanently to the MALL
// path — subsequent chunk launches skip probing entirely. Correctness does
// not depend on the workgroup->XCD assignment.
// ---------------------------------------------------------------------------
__global__ __launch_bounds__(1024)
void lstm4(const float* __restrict__ xg, const float* __restrict__ starts,
           const float* __restrict__ h0g, const float* __restrict__ c0g,
           float* __restrict__ hstate, float* __restrict__ cstate,
           const float* __restrict__ Wg,
           float* __restrict__ hs, float* __restrict__ hT,
           float* __restrict__ cT,
           u64* __restrict__ hx, u64* __restrict__ hx2,
           unsigned* __restrict__ fastState,
           int base, int fastflag)
{
    __shared__ float hmask[256];
    __shared__ float part[16][64][4];   // 16 KB

    const int t    = threadIdx.x;
    const int bid  = blockIdx.x;
    const int slot = bid >> 3;               // 0..31
    const int seq  = (bid & 7) + 8 * (slot >> 2);
    const int p    = slot & 3;
    const int u    = t & 63;
    const int q    = t >> 6;            // 0..15 (wave-uniform)

    // weights into registers: 16 float4 (64 VGPRs)
    float4 Wr[16];
#pragma unroll
    for (int kk = 0; kk < 16; ++kk)
        Wr[kk] = *(const float4*)(Wg + (size_t)(q * 16 + kk) * 1024 + (p * 64 + u) * 4);

    float c_reg = 0.f;
    if (t < 64) {
        const float* csrc = (base == 0) ? c0g : cstate;
        c_reg = csrc[(size_t)seq * 256 + p * 64 + t];
    }

    // launch-persistent verdict: if any probe already failed, skip fast path
    bool useFast = (fastflag != 0);
    if (useFast) {
        unsigned st = __hip_atomic_load(fastState, __ATOMIC_RELAXED,
                                        __HIP_MEMORY_SCOPE_AGENT);
        if (st != 0u) useFast = false;
    }

    for (int lt = 0; lt < CS; ++lt) {
        const int S = base + lt;
        const float m = 1.f - starts[(size_t)seq * TSEQ + S];

        // prefetch xg for owners (independent of exchange)
        float4 x4 = make_float4(0.f, 0.f, 0.f, 0.f);
        if (t < 64)
            x4 = *(const float4*)(xg + ((size_t)seq * CS + lt) * 1024 + (p * 64 + t) * 4);

        if (lt == 0) {
            if (t < 256) {
                const float* hsrc = (base == 0) ? h0g : hstate;
                hmask[t] = hsrc[(size_t)seq * 256 + t] * m;
            }
        } else {
            if (t < 256) {
                const size_t idx = (size_t)(S & 1) * (NSEQ * 256) + (size_t)seq * 256 + t;
                u64 w = 0;
                if (useFast) {
                    int tries = 0;
                    for (;;) {
                        w = l2_load_u64(&hx2[idx]);
                        if ((unsigned)(w >> 32) == (unsigned)S) break;
                        if (++tries > 768) {
                            useFast = false;
                            __hip_atomic_store(fastState, 1u, __ATOMIC_RELAXED,
                                               __HIP_MEMORY_SCOPE_AGENT);
                            break;
                        }
                    }
                }
                if (!useFast) {
                    unsigned spins = 0;
                    for (;;) {
                        w = __hip_atomic_load(&hx[idx], __ATOMIC_RELAXED,
                                              __HIP_MEMORY_SCOPE_AGENT);
                        if ((unsigned)(w >> 32) == (unsigned)S) break;
                        __builtin_amdgcn_s_sleep(1);
                        if (++spins > (1u << 18)) break;   // safety valve
                    }
                }
                hmask[t] = __uint_as_float((unsigned)w) * m;
            }
        }
        __syncthreads();   // A: hmask ready

        // partial dot over k in [q*16, q*16+16) for unit u, 4 gates
        const float* hp = &hmask[q * 16];
        float4 h0 = *(const float4*)(hp + 0);
        float4 h1 = *(const float4*)(hp + 4);
        float4 h2 = *(const float4*)(hp + 8);
        float4 h3 = *(const float4*)(hp + 12);
        float hv[16] = {h0.x,h0.y,h0.z,h0.w, h1.x,h1.y,h1.z,h1.w,
                        h2.x,h2.y,h2.z,h2.w, h3.x,h3.y,h3.z,h3.w};
        float a0 = 0.f, a1 = 0.f, a2 = 0.f, a3 = 0.f;
#pragma unroll
        for (int kk = 0; kk < 16; ++kk) {
            a0 += hv[kk] * Wr[kk].x;
            a1 += hv[kk] * Wr[kk].y;
            a2 += hv[kk] * Wr[kk].z;
            a3 += hv[kk] * Wr[kk].w;
        }
        *(float4*)&part[q][u][0] = make_float4(a0, a1, a2, a3);
        __syncthreads();   // B: partials ready

        if (t < 64) {
            float gi = 0.f, gf = 0.f, gg = 0.f, go = 0.f;
#pragma unroll
            for (int qq = 0; qq < 16; ++qq) {
                float4 pp = *(const float4*)&part[qq][t][0];
                gi += pp.x; gf += pp.y; gg += pp.z; go += pp.w;
            }
            gi += x4.x; gf += x4.y; gg += x4.z; go += x4.w;
            float c = c_reg * m;
            float si = 1.f / (1.f + expf(-gi));
            float sf = 1.f / (1.f + expf(-gf));
            float so = 1.f / (1.f + expf(-go));
            c = sf * c + si * tanhf(gg);
            float h = so * tanhf(c);
            c_reg = c;

            const int gu = p * 64 + t;
            const size_t widx = (size_t)((S + 1) & 1) * (NSEQ * 256)
                              + (size_t)seq * 256 + gu;
            const u64 pkt = ((u64)(unsigned)(S + 1) << 32)
                          | (u64)__float_as_uint(h);
            if (fastflag) l2_store_u64(&hx2[widx], pkt);   // fast L2 publish
            __hip_atomic_store(&hx[widx], pkt,
                               __ATOMIC_RELAXED, __HIP_MEMORY_SCOPE_AGENT);
            hs[((size_t)seq * CS + lt) * 256 + gu] = h;
            if (lt == CS - 1) {
                cstate[(size_t)seq * 256 + gu] = c;
                hstate[(size_t)seq * 256 + gu] = h;
            }
            if (S == TSEQ - 1) {
                cT[(size_t)seq * 256 + gu] = c;
                hT[(size_t)seq * 256 + gu] = h;
            }
        }
        // no trailing barrier needed: next iteration's first barrier (A)
        // orders part[]/hmask reuse; hx poll is global-tag-gated.
    }
}

// ---------------------------------------------------------------------------
// gemm_latent (chunk): lat[lr][n] (n<768: feats@W_feat^T + b_feat;
// n>=768: feats@W_emb^T + b_emb). fp64 masters, 128x128 tile, 8x8/thread.
// grid (8, 64). Per-element accumulation order identical to the old 64x64
// version (fp32 within each 16-k tile, fp64 across tiles) => bit-identical.
// 768 % 128 == 0, so the Wfeat/Wemb row split is tile-aligned.
// ---------------------------------------------------------------------------
__global__ __launch_bounds__(256)
void gemm_latent(const float* __restrict__ A, const float* __restrict__ Wfeat,
                 const float* __restrict__ Wemb, const float* __restrict__ bfeat,
                 const float* __restrict__ bemb, float* __restrict__ lat, int base)
{
    __shared__ float As[16][136];
    __shared__ float Bs[16][136];
    const int t  = threadIdx.x;
    const int n0 = blockIdx.x * 128;
    const size_t lr0 = (size_t)blockIdx.y * 128;          // one seq's chunk block
    const size_t grow0 = (lr0 >> 7) * TSEQ + base;        // lr0 % 128 == 0
    const int tx = t & 15, ty = t >> 4;

    double acc[8][8];
#pragma unroll
    for (int i = 0; i < 8; ++i)
#pragma unroll
        for (int j = 0; j < 8; ++j) acc[i][j] = 0.0;

    for (int kt = 0; kt < 256; kt += 16) {
#pragma unroll
        for (int jj = 0; jj < 2; ++jj) {
            int idx = t + 256 * jj;
            int m = idx >> 2, q = idx & 3;
            float4 a = *(const float4*)(A + (grow0 + m) * 256 + kt + q * 4);
            As[q * 4 + 0][m] = a.x; As[q * 4 + 1][m] = a.y;
            As[q * 4 + 2][m] = a.z; As[q * 4 + 3][m] = a.w;
            int n = n0 + m;
            const float* Brow = (n < 768) ? (Wfeat + (size_t)n * 256)
                                          : (Wemb + (size_t)(n - 768) * 256);
            float4 b = *(const float4*)(Brow + kt + q * 4);
            Bs[q * 4 + 0][m] = b.x; Bs[q * 4 + 1][m] = b.y;
            Bs[q * 4 + 2][m] = b.z; Bs[q * 4 + 3][m] = b.w;
        }
        __syncthreads();
        float p[8][8];
#pragma unroll
        for (int i = 0; i < 8; ++i)
#pragma unroll
            for (int j = 0; j < 8; ++j) p[i][j] = 0.f;
#pragma unroll
        for (int k = 0; k < 16; ++k) {
            float4 a0 = *(const float4*)&As[k][ty * 8];
            float4 a1 = *(const float4*)&As[k][ty * 8 + 4];
            float4 b0 = *(const float4*)&Bs[k][tx * 8];
            float4 b1 = *(const float4*)&Bs[k][tx * 8 + 4];
            float av[8] = {a0.x, a0.y, a0.z, a0.w, a1.x, a1.y, a1.z, a1.w};
            float bv[8] = {b0.x, b0.y, b0.z, b0.w, b1.x, b1.y, b1.z, b1.w};
#pragma unroll
            for (int i = 0; i < 8; ++i)
#pragma unroll
                for (int j = 0; j < 8; ++j) p[i][j] += av[i] * bv[j];
        }
#pragma unroll
        for (int i = 0; i < 8; ++i)
#pragma unroll
            for (int j = 0; j < 8; ++j) acc[i][j] += (double)p[i][j];
        __syncthreads();
    }
#pragma unroll
    for (int i = 0; i < 8; ++i) {
        size_t lr = lr0 + ty * 8 + i;
#pragma unroll
        for (int j = 0; j < 8; ++j) {
            int n = n0 + tx * 8 + j;
            float v = (float)acc[i][j];
            v += (n < 768) ? bfeat[n] : bemb[n - 768];
            lat[lr * 1024 + n] = v;
        }
    }
}

// ---------------------------------------------------------------------------
// gemm_h1p (chunk): h1[lr][n] = relu(lat[lr] @ Wp1[n]^T + bp1[n]), K=1024.
// fp64 masters, 128x128 tile, 8x8/thread. grid (4, 64).
// Accumulation order per element identical to old 64x64 version.
// ---------------------------------------------------------------------------
__global__ __launch_bounds__(256)
void gemm_h1p(const float* __restrict__ lat, const float* __restrict__ Wp1,
              const float* __restrict__ bp1, float* __restrict__ h1)
{
    __shared__ float As[16][136];
    __shared__ float Bs[16][136];
    const int t  = threadIdx.x;
    const int n0 = blockIdx.x * 128;
    const size_t lr0 = (size_t)blockIdx.y * 128;
    const int tx = t & 15, ty = t >> 4;

    double acc[8][8];
#pragma unroll
    for (int i = 0; i < 8; ++i)
#pragma unroll
        for (int j = 0; j < 8; ++j) acc[i][j] = 0.0;

    for (int kt = 0; kt < 1024; kt += 16) {
#pragma unroll
        for (int jj = 0; jj < 2; ++jj) {
            int idx = t + 256 * jj;
            int m = idx >> 2, q = idx & 3;
            float4 a = *(const float4*)(lat + (lr0 + m) * 1024 + kt + q * 4);
            As[q * 4 + 0][m] = a.x; As[q * 4 + 1][m] = a.y;
            As[q * 4 + 2][m] = a.z; As[q * 4 + 3][m] = a.w;
            float4 b = *(const float4*)(Wp1 + (size_t)(n0 + m) * 1024 + kt + q * 4);
            Bs[q * 4 + 0][m] = b.x; Bs[q * 4 + 1][m] = b.y;
            Bs[q * 4 + 2][m] = b.z; Bs[q * 4 + 3][m] = b.w;
        }
        __syncthreads();
        float p[8][8];
#pragma unroll
        for (int i = 0; i < 8; ++i)
#pragma unroll
            for (int j = 0; j < 8; ++j) p[i][j] = 0.f;
#pragma unroll
        for (int k = 0; k < 16; ++k) {
            float4 a0 = *(const float4*)&As[k][ty * 8];
            float4 a1 = *(const float4*)&As[k][ty * 8 + 4];
            float4 b0 = *(const float4*)&Bs[k][tx * 8];
            float4 b1 = *(const float4*)&Bs[k][tx * 8 + 4];
            float av[8] = {a0.x, a0.y, a0.z, a0.w, a1.x, a1.y, a1.z, a1.w};
            float bv[8] = {b0.x, b0.y, b0.z, b0.w, b1.x, b1.y, b1.z, b1.w};
#pragma unroll
            for (int i = 0; i < 8; ++i)
#pragma unroll
                for (int j = 0; j < 8; ++j) p[i][j] += av[i] * bv[j];
        }
#pragma unroll
        for (int i = 0; i < 8; ++i)
#pragma unroll
            for (int j = 0; j < 8; ++j) acc[i][j] += (double)p[i][j];
        __syncthreads();
    }
#pragma unroll
    for (int i = 0; i < 8; ++i) {
        size_t lr = lr0 + ty * 8 + i;
#pragma unroll
        for (int j = 0; j < 8; ++j) {
            int n = n0 + tx * 8 + j;
            float v = (float)acc[i][j] + bp1[n];
            h1[lr * 512 + n] = v > 0.f ? v : 0.f;
        }
    }
}

// ---------------------------------------------------------------------------
// gemm_h1v (chunk): h1[lr][n] = relu(lat[lr][0:768]@Wv1[n][0:768]^T
//                                  + hs[lr]@Wv1[n][768:]^T + bv1[n])  fp32
// grid (4, 64): 128x128 tile, 8x8/thread.
// ---------------------------------------------------------------------------
__global__ __launch_bounds__(256)
void gemm_h1v(const float* __restrict__ lat, const float* __restrict__ hs,
              const float* __restrict__ Wv1, const float* __restrict__ bv1,
              float* __restrict__ h1)
{
    __shared__ float As[16][136];
    __shared__ float Bs[16][136];
    const int t  = threadIdx.x;
    const int n0 = blockIdx.x * 128;
    const size_t lrow0 = (size_t)blockIdx.y * 128;
    const int tx = t & 15, ty = t >> 4;

    float acc[8][8];
#pragma unroll
    for (int i = 0; i < 8; ++i)
#pragma unroll
        for (int j = 0; j < 8; ++j) acc[i][j] = 0.f;

    for (int pass = 0; pass < 2; ++pass) {
        const float* A  = (pass == 0) ? lat : hs;
        const int lda   = (pass == 0) ? 1024 : 256;
        const int kmax  = (pass == 0) ? 768 : 256;
        const int boff  = (pass == 0) ? 0 : 768;
        for (int kt = 0; kt < kmax; kt += 16) {
#pragma unroll
            for (int jj = 0; jj < 2; ++jj) {
                int idx = t + 256 * jj;
                int m = idx >> 2, q = idx & 3;
                float4 a = *(const float4*)(A + (lrow0 + m) * lda + kt + q * 4);
                As[q * 4 + 0][m] = a.x; As[q * 4 + 1][m] = a.y;
                As[q * 4 + 2][m] = a.z; As[q * 4 + 3][m] = a.w;
                float4 b = *(const float4*)(Wv1 + (size_t)(n0 + m) * 1024 + boff + kt + q * 4);
                Bs[q * 4 + 0][m] = b.x; Bs[q * 4 + 1][m] = b.y;
                Bs[q * 4 + 2][m] = b.z; Bs[q * 4 + 3][m] = b.w;
            }
            __syncthreads();
#pragma unroll
            for (int k = 0; k < 16; ++k) {
                float4 a0 = *(const float4*)&As[k][ty * 8];
                float4 a1 = *(const float4*)&As[k][ty * 8 + 4];
                float4 b0 = *(const float4*)&Bs[k][tx * 8];
                float4 b1 = *(const float4*)&Bs[k][tx * 8 + 4];
                float av[8] = {a0.x, a0.y, a0.z, a0.w, a1.x, a1.y, a1.z, a1.w};
                float bv[8] = {b0.x, b0.y, b0.z, b0.w, b1.x, b1.y, b1.z, b1.w};
#pragma unroll
                for (int i = 0; i < 8; ++i)
#pragma unroll
                    for (int j = 0; j < 8; ++j) acc[i][j] += av[i] * bv[j];
            }
            __syncthreads();
        }
    }
#pragma unroll
    for (int i = 0; i < 8; ++i) {
        size_t lr = lrow0 + ty * 8 + i;
#pragma unroll
        for (int j = 0; j < 8; ++j) {
            int n = n0 + tx * 8 + j;
            float v = acc[i][j] + bv1[n];
            h1[lr * 512 + n] = v > 0.f ? v : 0.f;
        }
    }
}

// ---------------------------------------------------------------------------
__global__ __launch_bounds__(256)
void mask_kernel(const float* __restrict__ starts, const float* __restrict__ h_pi,
                 const float* __restrict__ c_pi,
                 float* __restrict__ o_hpi, float* __restrict__ o_cpi)
{
    __shared__ float red[256];
    const int n = blockIdx.x, t = threadIdx.x;
    float a = 0.f;
    for (int j = 0; j < 8; ++j)
        a = fmaxf(a, starts[(size_t)n * TSEQ + t * 8 + j]);
    red[t] = a; __syncthreads();
    for (int s = 128; s > 0; s >>= 1) {
        if (t < s) red[t] = fmaxf(red[t], red[t + s]);
        __syncthreads();
    }
    float m = (red[0] > 0.f) ? 0.f : 1.f;
    o_hpi[(size_t)n * 256 + t] = h_pi[(size_t)n * 256 + t] * m;
    o_cpi[(size_t)n * 256 + t] = c_pi[(size_t)n * 256 + t] * m;
}

// ---------------------------------------------------------------------------
// policy_finish (chunk): logits (fp64 dot) -> argmax, log-softmax pick.
// ---------------------------------------------------------------------------
__global__ __launch_bounds__(256)
void policy_finish(const float* __restrict__ h1p, const float* __restrict__ Wp2,
                   const float* __restrict__ bp2,
                   float* __restrict__ o_actions, float* __restrict__ o_logp,
                   int base)
{
    __shared__ float w2t[512 * 32];   // [k][c]
    const int t = threadIdx.x;
    for (int j = 0; j < 64; ++j) {
        int idx = t + 256 * j;
        int k = idx >> 5, c = idx & 31;
        w2t[idx] = Wp2[(size_t)c * 512 + k];
    }
    __syncthreads();

    const int c = t & 31;
    size_t lr = (size_t)blockIdx.x * 8 + (t >> 5);
    size_t grow = (lr >> 7) * TSEQ + base + (lr & 127);
    const float* hrow = h1p + lr * 512;
    double s = 0.0;
    for (int k = 0; k < 512; k += 4) {
        float4 h4 = *(const float4*)(hrow + k);
        s += (double)h4.x * (double)w2t[(k + 0) * 32 + c];
        s += (double)h4.y * (double)w2t[(k + 1) * 32 + c];
        s += (double)h4.z * (double)w2t[(k + 2) * 32 + c];
        s += (double)h4.w * (double)w2t[(k + 3) * 32 + c];
    }
    double logit = s + (double)bp2[c];

    double mv = logit; int mi = c;
#pragma unroll
    for (int off = 16; off >= 1; off >>= 1) {
        double ov = __shfl_xor(mv, off, 32);
        int    oi = __shfl_xor(mi, off, 32);
        if (ov > mv || (ov == mv && oi < mi)) { mv = ov; mi = oi; }
    }
    double se = exp(logit - mv);
#pragma unroll
    for (int off = 16; off >= 1; off >>= 1) se += __shfl_xor(se, off, 32);

    if (c == 0) {
        o_actions[grow] = (float)mi;
        o_logp[grow]    = (float)(-log(se));
    }
}

// ---------------------------------------------------------------------------
// value_finish (chunk): values = h1v . Wv2 + bv2. 64 rows x 4 lanes; 128 blocks.
// ---------------------------------------------------------------------------
__global__ __launch_bounds__(256)
void value_finish(const float* __restrict__ h1v, const float* __restrict__ Wv2,
                  const float* __restrict__ bv2, float* __restrict__ o_values,
                  int base)
{
    __shared__ float wv[512];
    const int t = threadIdx.x;
    wv[t] = Wv2[t]; wv[t + 256] = Wv2[t + 256];
    __syncthreads();
    const int q = t & 3;
    size_t lr = (size_t)blockIdx.x * 64 + (t >> 2);
    size_t grow = (lr >> 7) * TSEQ + base + (lr & 127);
    const float* hrow = h1v + lr * 512;
    float s = 0.f;
    for (int k = q * 128; k < q * 128 + 128; k += 4) {
        float4 h4 = *(const float4*)(hrow + k);
        float4 w4 = *(const float4*)&wv[k];
        s += h4.x * w4.x + h4.y * w4.y + h4.z * w4.z + h4.w * w4.w;
    }
    s += __shfl_xor(s, 1, 4);
    s += __shfl_xor(s, 2, 4);
    if (q == 0) o_values[grow] = s + bv2[0];
}

// ---------------------------------------------------------------------------
extern "C" void kernel_launch(void* const* d_in, const int* in_sizes, int n_in,
                              void* d_out, int out_size, void* d_ws, size_t ws_size,
                              hipStream_t stream)
{
    const float* features = (const float*)d_in[0];
    const float* starts   = (const float*)d_in[1];
    const float* h_pi     = (const float*)d_in[2];
    const float* c_pi     = (const float*)d_in[3];
    const float* h_vf     = (const float*)d_in[4];
    const float* c_vf     = (const float*)d_in[5];
    const float* W_feat   = (const float*)d_in[6];
    const float* b_feat   = (const float*)d_in[7];
    const float* W_emb    = (const float*)d_in[8];
    const float* b_emb    = (const float*)d_in[9];
    const float* W_ih     = (const float*)d_in[10];
    const float* W_hh     = (const float*)d_in[11];
    const float* b_ih     = (const float*)d_in[12];
    const float* b_hh     = (const float*)d_in[13];
    const float* Wp1      = (const float*)d_in[14];
    const float* bp1      = (const float*)d_in[15];
    const float* Wp2      = (const float*)d_in[16];
    const float* bp2      = (const float*)d_in[17];
    const float* Wv1      = (const float*)d_in[18];
    const float* bv1      = (const float*)d_in[19];
    const float* Wv2      = (const float*)d_in[20];
    const float* bv2      = (const float*)d_in[21];

    float* out = (float*)d_out;
    float* o_actions = out;
    float* o_values  = out + N_TOT;
    float* o_logp    = out + 2 * (size_t)N_TOT;
    float* o_hpi     = out + 3 * (size_t)N_TOT;
    float* o_cpi     = o_hpi + NSEQ * 256;
    float* o_hT      = o_cpi + NSEQ * 256;
    float* o_cT      = o_hT  + NSEQ * 256;

    // workspace (~89.7 MB)
    char* ws = (char*)d_ws;
    const size_t MB = 1024 * 1024;
    float* xg_c  = (float*)(ws);                 // 32 MB  (8192 x 1024)
    float* lat_c = (float*)(ws + 32 * MB);       // 32 MB  (8192 x 1024)
    float* hs_c  = (float*)(ws + 64 * MB);       //  8 MB  (8192 x 256)
    float* h1_c  = (float*)(ws + 72 * MB);       // 16 MB  (8192 x 512)
    float* Wg    = (float*)(ws + 88 * MB);       //  1 MB
    float* hstate = (float*)(ws + 89 * MB);                  // 64 KB
    float* cstate = (float*)(ws + 89 * MB + 65536);          // 64 KB
    u64*   hx     = (u64*)  (ws + 89 * MB + 131072);         // 256 KB (2x64x256 u64) MALL path
    u64*   hx2    = (u64*)  (ws + 89 * MB + 393216);         // 256 KB L2 fast path
    unsigned* fastState = (unsigned*)(ws + 89 * MB + 655360); // 4 B verdict flag

    // fast L2 exchange only if workspace has room for hx2 + fastState
    const int fastflag = (ws_size >= 89 * MB + 656 * 1024) ? 1 : 0;
    u64* hx2_eff = fastflag ? hx2 : hx;           // unused when fastflag==0
    unsigned* fs_eff = fastflag ? fastState : (unsigned*)hx;

    transpose_whh<<<256, 256, 0, stream>>>(W_hh, Wg);

    mask_kernel<<<NSEQ, 256, 0, stream>>>(starts, h_pi, c_pi, o_hpi, o_cpi);

    for (int c = 0; c < NCH; ++c) {
        const int base = c * CS;

        gemm_xg<<<dim3(8, NSEQ), 256, 0, stream>>>(features, W_ih, b_ih, b_hh,
                                                   xg_c, base);
        lstm4<<<NSEQ * PARTS, 1024, 0, stream>>>(xg_c, starts, h_vf, c_vf,
                                                 hstate, cstate, Wg,
                                                 hs_c, o_hT, o_cT, hx, hx2_eff,
                                                 fs_eff, base, fastflag);

        gemm_latent<<<dim3(8, 64), 256, 0, stream>>>(
            features, W_feat, W_emb, b_feat, b_emb, lat_c, base);

        gemm_h1p<<<dim3(4, 64), 256, 0, stream>>>(lat_c, Wp1, bp1, h1_c);
        policy_finish<<<1024, 256, 0, stream>>>(h1_c, Wp2, bp2,
                                                o_actions, o_logp, base);

        gemm_h1v<<<dim3(4, 64), 256, 0, stream>>>(lat_c, hs_c, Wv1, bv1, h1_c);
        value_finish<<<128, 256, 0, stream>>>(h1_c, Wv2, bv2, o_values, base);
    }
}

// Round 5
// 14740.810 us; speedup vs baseline: 1.1297x; 1.1297x over previous
//
#include <hip/hip_runtime.h>
#include <stdint.h>
#include <math.h>

#define N_TOT 131072   // NSEQ * T
#define TSEQ  2048
#define NSEQ  64
#define CS    128      // chunk steps
#define NCH   16       // chunks
#define PARTS 4        // WGs per sequence

typedef unsigned long long u64;

// ---------------------------------------------------------------------------
// One-time: transpose W_hh (1024x256, row = gate*256+u) into
// Wg[k][u][gate]  (k-major, unit, 4 gates contiguous).
// ---------------------------------------------------------------------------
__global__ __launch_bounds__(256)
void transpose_whh(const float* __restrict__ Whh, float* __restrict__ Wg)
{
    const int k = blockIdx.x;     // 0..255
    const int u = threadIdx.x;    // 0..255
#pragma unroll
    for (int g = 0; g < 4; ++g)
        Wg[(size_t)k * 1024 + u * 4 + g] = Whh[(size_t)(g * 256 + u) * 256 + k];
}

// ---------------------------------------------------------------------------
// gemm_xg (chunk): xg[lr][u*4+g] = feats @ W_ih^T + b_ih + b_hh  (permuted)
// grid (8, 64): bx = n-tile, by = seq. fp32, 128x128 tile, 8x8 reg block.
// ---------------------------------------------------------------------------
__global__ __launch_bounds__(256)
void gemm_xg(const float* __restrict__ A, const float* __restrict__ Wih,
             const float* __restrict__ bih, const float* __restrict__ bhh,
             float* __restrict__ xg, int base)
{
    __shared__ float As[16][136];
    __shared__ float Bs[16][136];
    const int t  = threadIdx.x;
    const int n0 = blockIdx.x * 128;
    const int seq = blockIdx.y;
    const size_t grow0 = (size_t)seq * TSEQ + base;
    const size_t lrow0 = (size_t)seq * CS;
    const int tx = t & 15, ty = t >> 4;

    float acc[8][8];
#pragma unroll
    for (int i = 0; i < 8; ++i)
#pragma unroll
        for (int j = 0; j < 8; ++j) acc[i][j] = 0.f;

    for (int kt = 0; kt < 256; kt += 16) {
#pragma unroll
        for (int jj = 0; jj < 2; ++jj) {
            int idx = t + 256 * jj;
            int m = idx >> 2, q = idx & 3;
            float4 a = *(const float4*)(A + (grow0 + m) * 256 + kt + q * 4);
            As[q * 4 + 0][m] = a.x; As[q * 4 + 1][m] = a.y;
            As[q * 4 + 2][m] = a.z; As[q * 4 + 3][m] = a.w;
            float4 b = *(const float4*)(Wih + (size_t)(n0 + m) * 256 + kt + q * 4);
            Bs[q * 4 + 0][m] = b.x; Bs[q * 4 + 1][m] = b.y;
            Bs[q * 4 + 2][m] = b.z; Bs[q * 4 + 3][m] = b.w;
        }
        __syncthreads();
#pragma unroll
        for (int k = 0; k < 16; ++k) {
            float4 a0 = *(const float4*)&As[k][ty * 8];
            float4 a1 = *(const float4*)&As[k][ty * 8 + 4];
            float4 b0 = *(const float4*)&Bs[k][tx * 8];
            float4 b1 = *(const float4*)&Bs[k][tx * 8 + 4];
            float av[8] = {a0.x, a0.y, a0.z, a0.w, a1.x, a1.y, a1.z, a1.w};
            float bv[8] = {b0.x, b0.y, b0.z, b0.w, b1.x, b1.y, b1.z, b1.w};
#pragma unroll
            for (int i = 0; i < 8; ++i)
#pragma unroll
                for (int j = 0; j < 8; ++j) acc[i][j] += av[i] * bv[j];
        }
        __syncthreads();
    }
#pragma unroll
    for (int i = 0; i < 8; ++i) {
        size_t lr = lrow0 + ty * 8 + i;
#pragma unroll
        for (int j = 0; j < 8; ++j) {
            int n = n0 + tx * 8 + j;      // gate-major index 0..1023
            int gate = n >> 8, u = n & 255;
            xg[lr * 1024 + u * 4 + gate] = acc[i][j] + bih[n] + bhh[n];
        }
    }
}

// ---------------------------------------------------------------------------
// L2-path 8-byte exchange primitives (same-XCD shared L2).
// ---------------------------------------------------------------------------
__device__ __forceinline__ void l2_store_u64(u64* p, u64 v)
{
    asm volatile("global_store_dwordx2 %0, %1, off"
                 :: "v"(p), "v"(v) : "memory");
}

__device__ __forceinline__ u64 l2_load_u64(const u64* p)
{
    u64 v;
    asm volatile("global_load_dwordx2 %0, %1, off sc0\n\t"
                 "s_waitcnt vmcnt(0)"
                 : "=v"(v) : "v"(p) : "memory");
    return v;
}

// ---------------------------------------------------------------------------
// FUSED lstm4 + gemm_h1p.
//   bids 0..255   : lstm4 body (identical math/mapping to the proven kernel).
//   bids 256..511 : gemm_h1p, 4 sub-blocks x 256 threads, each a 64x64 tile
//                   (the round-2-validated fp64-master variant; VGPR <= ~100
//                   so a 1024-thread WG fits at <=128 VGPR).
// h1p(c) depends only on lat_c (computed before this launch) and is
// independent of the lstm chain -> fills lstm4's idle CU slots.
// LDS: union of lstm (17408 B) and h1p 4x(2x16x72 floats) = 36864 B.
// ---------------------------------------------------------------------------
__global__ __launch_bounds__(1024)
void lstm4_h1p(const float* __restrict__ xg, const float* __restrict__ starts,
               const float* __restrict__ h0g, const float* __restrict__ c0g,
               float* __restrict__ hstate, float* __restrict__ cstate,
               const float* __restrict__ Wg,
               float* __restrict__ hs, float* __restrict__ hT,
               float* __restrict__ cT,
               u64* __restrict__ hx, u64* __restrict__ hx2,
               unsigned* __restrict__ fastState,
               const float* __restrict__ lat, const float* __restrict__ Wp1,
               const float* __restrict__ bp1, float* __restrict__ h1,
               int base, int fastflag)
{
    __shared__ float smem[9216];   // 36864 B

    const int t   = threadIdx.x;
    const int bid = blockIdx.x;

    if (bid < 256) {
        // ------------------------- lstm role -------------------------------
        float* hmask = smem;               // 256 floats
        float* part  = smem + 256;         // [16][64][4] = 4096 floats

        const int slot = bid >> 3;               // 0..31
        const int seq  = (bid & 7) + 8 * (slot >> 2);
        const int p    = slot & 3;
        const int u    = t & 63;
        const int q    = t >> 6;            // 0..15 (wave-uniform)

        float4 Wr[16];
#pragma unroll
        for (int kk = 0; kk < 16; ++kk)
            Wr[kk] = *(const float4*)(Wg + (size_t)(q * 16 + kk) * 1024 + (p * 64 + u) * 4);

        float c_reg = 0.f;
        if (t < 64) {
            const float* csrc = (base == 0) ? c0g : cstate;
            c_reg = csrc[(size_t)seq * 256 + p * 64 + t];
        }

        bool useFast = (fastflag != 0);
        if (useFast) {
            unsigned st = __hip_atomic_load(fastState, __ATOMIC_RELAXED,
                                            __HIP_MEMORY_SCOPE_AGENT);
            if (st != 0u) useFast = false;
        }

        for (int lt = 0; lt < CS; ++lt) {
            const int S = base + lt;
            const float m = 1.f - starts[(size_t)seq * TSEQ + S];

            float4 x4 = make_float4(0.f, 0.f, 0.f, 0.f);
            if (t < 64)
                x4 = *(const float4*)(xg + ((size_t)seq * CS + lt) * 1024 + (p * 64 + t) * 4);

            if (lt == 0) {
                if (t < 256) {
                    const float* hsrc = (base == 0) ? h0g : hstate;
                    hmask[t] = hsrc[(size_t)seq * 256 + t] * m;
                }
            } else {
                if (t < 256) {
                    const size_t idx = (size_t)(S & 1) * (NSEQ * 256) + (size_t)seq * 256 + t;
                    u64 w = 0;
                    if (useFast) {
                        int tries = 0;
                        for (;;) {
                            w = l2_load_u64(&hx2[idx]);
                            if ((unsigned)(w >> 32) == (unsigned)S) break;
                            if (++tries > 768) {
                                useFast = false;
                                __hip_atomic_store(fastState, 1u, __ATOMIC_RELAXED,
                                                   __HIP_MEMORY_SCOPE_AGENT);
                                break;
                            }
                        }
                    }
                    if (!useFast) {
                        unsigned spins = 0;
                        for (;;) {
                            w = __hip_atomic_load(&hx[idx], __ATOMIC_RELAXED,
                                                  __HIP_MEMORY_SCOPE_AGENT);
                            if ((unsigned)(w >> 32) == (unsigned)S) break;
                            __builtin_amdgcn_s_sleep(1);
                            if (++spins > (1u << 18)) break;   // safety valve
                        }
                    }
                    hmask[t] = __uint_as_float((unsigned)w) * m;
                }
            }
            __syncthreads();   // A: hmask ready

            const float* hp = &hmask[q * 16];
            float4 h0 = *(const float4*)(hp + 0);
            float4 h1v_ = *(const float4*)(hp + 4);
            float4 h2 = *(const float4*)(hp + 8);
            float4 h3 = *(const float4*)(hp + 12);
            float hv[16] = {h0.x,h0.y,h0.z,h0.w, h1v_.x,h1v_.y,h1v_.z,h1v_.w,
                            h2.x,h2.y,h2.z,h2.w, h3.x,h3.y,h3.z,h3.w};
            float a0 = 0.f, a1 = 0.f, a2 = 0.f, a3 = 0.f;
#pragma unroll
            for (int kk = 0; kk < 16; ++kk) {
                a0 += hv[kk] * Wr[kk].x;
                a1 += hv[kk] * Wr[kk].y;
                a2 += hv[kk] * Wr[kk].z;
                a3 += hv[kk] * Wr[kk].w;
            }
            *(float4*)&part[(q * 64 + u) * 4] = make_float4(a0, a1, a2, a3);
            __syncthreads();   // B: partials ready

            if (t < 64) {
                float gi = 0.f, gf = 0.f, gg = 0.f, go = 0.f;
#pragma unroll
                for (int qq = 0; qq < 16; ++qq) {
                    float4 pp = *(const float4*)&part[(qq * 64 + t) * 4];
                    gi += pp.x; gf += pp.y; gg += pp.z; go += pp.w;
                }
                gi += x4.x; gf += x4.y; gg += x4.z; go += x4.w;
                float c = c_reg * m;
                float si = 1.f / (1.f + expf(-gi));
                float sf = 1.f / (1.f + expf(-gf));
                float so = 1.f / (1.f + expf(-go));
                c = sf * c + si * tanhf(gg);
                float h = so * tanhf(c);
                c_reg = c;

                const int gu = p * 64 + t;
                const size_t widx = (size_t)((S + 1) & 1) * (NSEQ * 256)
                                  + (size_t)seq * 256 + gu;
                const u64 pkt = ((u64)(unsigned)(S + 1) << 32)
                              | (u64)__float_as_uint(h);
                if (fastflag) l2_store_u64(&hx2[widx], pkt);
                __hip_atomic_store(&hx[widx], pkt,
                                   __ATOMIC_RELAXED, __HIP_MEMORY_SCOPE_AGENT);
                hs[((size_t)seq * CS + lt) * 256 + gu] = h;
                if (lt == CS - 1) {
                    cstate[(size_t)seq * 256 + gu] = c;
                    hstate[(size_t)seq * 256 + gu] = h;
                }
                if (S == TSEQ - 1) {
                    cT[(size_t)seq * 256 + gu] = c;
                    hT[(size_t)seq * 256 + gu] = h;
                }
            }
        }
    } else {
        // ------------------------- h1p role --------------------------------
        // 4 sub-blocks x 256 threads; sub-block s handles tile (bid-256)*4+s
        // of the 64x64 grid: bx = tile & 7 (n), by = tile >> 3 (rows).
        const int s    = t >> 8;          // 0..3
        const int t2   = t & 255;
        const int tile = (bid - 256) * 4 + s;        // 0..1023
        const int n0   = (tile & 7) * 64;
        const size_t lr0 = (size_t)(tile >> 3) * 64;
        float* As = smem + s * 2304;      // 16x72
        float* Bs = As + 1152;            // 16x72
        const int tx = t2 & 15, ty = t2 >> 4;

        double acc[4][4];
#pragma unroll
        for (int i = 0; i < 4; ++i)
#pragma unroll
            for (int j = 0; j < 4; ++j) acc[i][j] = 0.0;

        for (int kt = 0; kt < 1024; kt += 16) {
            {
                int m = t2 >> 2, q = t2 & 3;
                float4 a = *(const float4*)(lat + (lr0 + m) * 1024 + kt + q * 4);
                As[(q * 4 + 0) * 72 + m] = a.x; As[(q * 4 + 1) * 72 + m] = a.y;
                As[(q * 4 + 2) * 72 + m] = a.z; As[(q * 4 + 3) * 72 + m] = a.w;
                float4 b = *(const float4*)(Wp1 + (size_t)(n0 + m) * 1024 + kt + q * 4);
                Bs[(q * 4 + 0) * 72 + m] = b.x; Bs[(q * 4 + 1) * 72 + m] = b.y;
                Bs[(q * 4 + 2) * 72 + m] = b.z; Bs[(q * 4 + 3) * 72 + m] = b.w;
            }
            __syncthreads();
            float p[4][4];
#pragma unroll
            for (int i = 0; i < 4; ++i)
#pragma unroll
                for (int j = 0; j < 4; ++j) p[i][j] = 0.f;
#pragma unroll
            for (int k = 0; k < 16; ++k) {
                float4 a0 = *(const float4*)&As[k * 72 + ty * 4];
                float4 b0 = *(const float4*)&Bs[k * 72 + tx * 4];
                float av[4] = {a0.x, a0.y, a0.z, a0.w};
                float bv[4] = {b0.x, b0.y, b0.z, b0.w};
#pragma unroll
                for (int i = 0; i < 4; ++i)
#pragma unroll
                    for (int j = 0; j < 4; ++j) p[i][j] += av[i] * bv[j];
            }
#pragma unroll
            for (int i = 0; i < 4; ++i)
#pragma unroll
                for (int j = 0; j < 4; ++j) acc[i][j] += (double)p[i][j];
            __syncthreads();
        }
#pragma unroll
        for (int i = 0; i < 4; ++i) {
            size_t lr = lr0 + ty * 4 + i;
#pragma unroll
            for (int j = 0; j < 4; ++j) {
                int n = n0 + tx * 4 + j;
                float v = (float)acc[i][j] + bp1[n];
                h1[lr * 512 + n] = v > 0.f ? v : 0.f;
            }
        }
    }
}

// ---------------------------------------------------------------------------
// gemm_latent (chunk): lat[lr][n] (n<768: feats@W_feat^T + b_feat;
// n>=768: feats@W_emb^T + b_emb). fp64 masters, 128x128 tile, 8x8/thread.
// grid (8, 64). Validated round 4 (absmax 0.015625).
// ---------------------------------------------------------------------------
__global__ __launch_bounds__(256)
void gemm_latent(const float* __restrict__ A, const float* __restrict__ Wfeat,
                 const float* __restrict__ Wemb, const float* __restrict__ bfeat,
                 const float* __restrict__ bemb, float* __restrict__ lat, int base)
{
    __shared__ float As[16][136];
    __shared__ float Bs[16][136];
    const int t  = threadIdx.x;
    const int n0 = blockIdx.x * 128;
    const size_t lr0 = (size_t)blockIdx.y * 128;          // one seq's chunk block
    const size_t grow0 = (lr0 >> 7) * TSEQ + base;        // lr0 % 128 == 0
    const int tx = t & 15, ty = t >> 4;

    double acc[8][8];
#pragma unroll
    for (int i = 0; i < 8; ++i)
#pragma unroll
        for (int j = 0; j < 8; ++j) acc[i][j] = 0.0;

    for (int kt = 0; kt < 256; kt += 16) {
#pragma unroll
        for (int jj = 0; jj < 2; ++jj) {
            int idx = t + 256 * jj;
            int m = idx >> 2, q = idx & 3;
            float4 a = *(const float4*)(A + (grow0 + m) * 256 + kt + q * 4);
            As[q * 4 + 0][m] = a.x; As[q * 4 + 1][m] = a.y;
            As[q * 4 + 2][m] = a.z; As[q * 4 + 3][m] = a.w;
            int n = n0 + m;
            const float* Brow = (n < 768) ? (Wfeat + (size_t)n * 256)
                                          : (Wemb + (size_t)(n - 768) * 256);
            float4 b = *(const float4*)(Brow + kt + q * 4);
            Bs[q * 4 + 0][m] = b.x; Bs[q * 4 + 1][m] = b.y;
            Bs[q * 4 + 2][m] = b.z; Bs[q * 4 + 3][m] = b.w;
        }
        __syncthreads();
        float p[8][8];
#pragma unroll
        for (int i = 0; i < 8; ++i)
#pragma unroll
            for (int j = 0; j < 8; ++j) p[i][j] = 0.f;
#pragma unroll
        for (int k = 0; k < 16; ++k) {
            float4 a0 = *(const float4*)&As[k][ty * 8];
            float4 a1 = *(const float4*)&As[k][ty * 8 + 4];
            float4 b0 = *(const float4*)&Bs[k][tx * 8];
            float4 b1 = *(const float4*)&Bs[k][tx * 8 + 4];
            float av[8] = {a0.x, a0.y, a0.z, a0.w, a1.x, a1.y, a1.z, a1.w};
            float bv[8] = {b0.x, b0.y, b0.z, b0.w, b1.x, b1.y, b1.z, b1.w};
#pragma unroll
            for (int i = 0; i < 8; ++i)
#pragma unroll
                for (int j = 0; j < 8; ++j) p[i][j] += av[i] * bv[j];
        }
#pragma unroll
        for (int i = 0; i < 8; ++i)
#pragma unroll
            for (int j = 0; j < 8; ++j) acc[i][j] += (double)p[i][j];
        __syncthreads();
    }
#pragma unroll
    for (int i = 0; i < 8; ++i) {
        size_t lr = lr0 + ty * 8 + i;
#pragma unroll
        for (int j = 0; j < 8; ++j) {
            int n = n0 + tx * 8 + j;
            float v = (float)acc[i][j];
            v += (n < 768) ? bfeat[n] : bemb[n - 768];
            lat[lr * 1024 + n] = v;
        }
    }
}

// ---------------------------------------------------------------------------
// gemm_h1v (chunk): h1[lr][n] = relu(lat[lr][0:768]@Wv1[n][0:768]^T
//                                  + hs[lr]@Wv1[n][768:]^T + bv1[n])  fp32
// grid (4, 64): 128x128 tile, 8x8/thread.
// ---------------------------------------------------------------------------
__global__ __launch_bounds__(256)
void gemm_h1v(const float* __restrict__ lat, const float* __restrict__ hs,
              const float* __restrict__ Wv1, const float* __restrict__ bv1,
              float* __restrict__ h1)
{
    __shared__ float As[16][136];
    __shared__ float Bs[16][136];
    const int t  = threadIdx.x;
    const int n0 = blockIdx.x * 128;
    const size_t lrow0 = (size_t)blockIdx.y * 128;
    const int tx = t & 15, ty = t >> 4;

    float acc[8][8];
#pragma unroll
    for (int i = 0; i < 8; ++i)
#pragma unroll
        for (int j = 0; j < 8; ++j) acc[i][j] = 0.f;

    for (int pass = 0; pass < 2; ++pass) {
        const float* A  = (pass == 0) ? lat : hs;
        const int lda   = (pass == 0) ? 1024 : 256;
        const int kmax  = (pass == 0) ? 768 : 256;
        const int boff  = (pass == 0) ? 0 : 768;
        for (int kt = 0; kt < kmax; kt += 16) {
#pragma unroll
            for (int jj = 0; jj < 2; ++jj) {
                int idx = t + 256 * jj;
                int m = idx >> 2, q = idx & 3;
                float4 a = *(const float4*)(A + (lrow0 + m) * lda + kt + q * 4);
                As[q * 4 + 0][m] = a.x; As[q * 4 + 1][m] = a.y;
                As[q * 4 + 2][m] = a.z; As[q * 4 + 3][m] = a.w;
                float4 b = *(const float4*)(Wv1 + (size_t)(n0 + m) * 1024 + boff + kt + q * 4);
                Bs[q * 4 + 0][m] = b.x; Bs[q * 4 + 1][m] = b.y;
                Bs[q * 4 + 2][m] = b.z; Bs[q * 4 + 3][m] = b.w;
            }
            __syncthreads();
#pragma unroll
            for (int k = 0; k < 16; ++k) {
                float4 a0 = *(const float4*)&As[k][ty * 8];
                float4 a1 = *(const float4*)&As[k][ty * 8 + 4];
                float4 b0 = *(const float4*)&Bs[k][tx * 8];
                float4 b1 = *(const float4*)&Bs[k][tx * 8 + 4];
                float av[8] = {a0.x, a0.y, a0.z, a0.w, a1.x, a1.y, a1.z, a1.w};
                float bv[8] = {b0.x, b0.y, b0.z, b0.w, b1.x, b1.y, b1.z, b1.w};
#pragma unroll
                for (int i = 0; i < 8; ++i)
#pragma unroll
                    for (int j = 0; j < 8; ++j) acc[i][j] += av[i] * bv[j];
            }
            __syncthreads();
        }
    }
#pragma unroll
    for (int i = 0; i < 8; ++i) {
        size_t lr = lrow0 + ty * 8 + i;
#pragma unroll
        for (int j = 0; j < 8; ++j) {
            int n = n0 + tx * 8 + j;
            float v = acc[i][j] + bv1[n];
            h1[lr * 512 + n] = v > 0.f ? v : 0.f;
        }
    }
}

// ---------------------------------------------------------------------------
__global__ __launch_bounds__(256)
void mask_kernel(const float* __restrict__ starts, const float* __restrict__ h_pi,
                 const float* __restrict__ c_pi,
                 float* __restrict__ o_hpi, float* __restrict__ o_cpi)
{
    __shared__ float red[256];
    const int n = blockIdx.x, t = threadIdx.x;
    float a = 0.f;
    for (int j = 0; j < 8; ++j)
        a = fmaxf(a, starts[(size_t)n * TSEQ + t * 8 + j]);
    red[t] = a; __syncthreads();
    for (int s = 128; s > 0; s >>= 1) {
        if (t < s) red[t] = fmaxf(red[t], red[t + s]);
        __syncthreads();
    }
    float m = (red[0] > 0.f) ? 0.f : 1.f;
    o_hpi[(size_t)n * 256 + t] = h_pi[(size_t)n * 256 + t] * m;
    o_cpi[(size_t)n * 256 + t] = c_pi[(size_t)n * 256 + t] * m;
}

// ---------------------------------------------------------------------------
// policy_finish (chunk): logits (fp64 dot) -> argmax, log-softmax pick.
// ---------------------------------------------------------------------------
__global__ __launch_bounds__(256)
void policy_finish(const float* __restrict__ h1p, const float* __restrict__ Wp2,
                   const float* __restrict__ bp2,
                   float* __restrict__ o_actions, float* __restrict__ o_logp,
                   int base)
{
    __shared__ float w2t[512 * 32];   // [k][c]
    const int t = threadIdx.x;
    for (int j = 0; j < 64; ++j) {
        int idx = t + 256 * j;
        int k = idx >> 5, c = idx & 31;
        w2t[idx] = Wp2[(size_t)c * 512 + k];
    }
    __syncthreads();

    const int c = t & 31;
    size_t lr = (size_t)blockIdx.x * 8 + (t >> 5);
    size_t grow = (lr >> 7) * TSEQ + base + (lr & 127);
    const float* hrow = h1p + lr * 512;
    double s = 0.0;
    for (int k = 0; k < 512; k += 4) {
        float4 h4 = *(const float4*)(hrow + k);
        s += (double)h4.x * (double)w2t[(k + 0) * 32 + c];
        s += (double)h4.y * (double)w2t[(k + 1) * 32 + c];
        s += (double)h4.z * (double)w2t[(k + 2) * 32 + c];
        s += (double)h4.w * (double)w2t[(k + 3) * 32 + c];
    }
    double logit = s + (double)bp2[c];

    double mv = logit; int mi = c;
#pragma unroll
    for (int off = 16; off >= 1; off >>= 1) {
        double ov = __shfl_xor(mv, off, 32);
        int    oi = __shfl_xor(mi, off, 32);
        if (ov > mv || (ov == mv && oi < mi)) { mv = ov; mi = oi; }
    }
    double se = exp(logit - mv);
#pragma unroll
    for (int off = 16; off >= 1; off >>= 1) se += __shfl_xor(se, off, 32);

    if (c == 0) {
        o_actions[grow] = (float)mi;
        o_logp[grow]    = (float)(-log(se));
    }
}

// ---------------------------------------------------------------------------
// value_finish (chunk): values = h1v . Wv2 + bv2. 64 rows x 4 lanes; 128 blocks.
// ---------------------------------------------------------------------------
__global__ __launch_bounds__(256)
void value_finish(const float* __restrict__ h1v, const float* __restrict__ Wv2,
                  const float* __restrict__ bv2, float* __restrict__ o_values,
                  int base)
{
    __shared__ float wv[512];
    const int t = threadIdx.x;
    wv[t] = Wv2[t]; wv[t + 256] = Wv2[t + 256];
    __syncthreads();
    const int q = t & 3;
    size_t lr = (size_t)blockIdx.x * 64 + (t >> 2);
    size_t grow = (lr >> 7) * TSEQ + base + (lr & 127);
    const float* hrow = h1v + lr * 512;
    float s = 0.f;
    for (int k = q * 128; k < q * 128 + 128; k += 4) {
        float4 h4 = *(const float4*)(hrow + k);
        float4 w4 = *(const float4*)&wv[k];
        s += h4.x * w4.x + h4.y * w4.y + h4.z * w4.z + h4.w * w4.w;
    }
    s += __shfl_xor(s, 1, 4);
    s += __shfl_xor(s, 2, 4);
    if (q == 0) o_values[grow] = s + bv2[0];
}

// ---------------------------------------------------------------------------
extern "C" void kernel_launch(void* const* d_in, const int* in_sizes, int n_in,
                              void* d_out, int out_size, void* d_ws, size_t ws_size,
                              hipStream_t stream)
{
    const float* features = (const float*)d_in[0];
    const float* starts   = (const float*)d_in[1];
    const float* h_pi     = (const float*)d_in[2];
    const float* c_pi     = (const float*)d_in[3];
    const float* h_vf     = (const float*)d_in[4];
    const float* c_vf     = (const float*)d_in[5];
    const float* W_feat   = (const float*)d_in[6];
    const float* b_feat   = (const float*)d_in[7];
    const float* W_emb    = (const float*)d_in[8];
    const float* b_emb    = (const float*)d_in[9];
    const float* W_ih     = (const float*)d_in[10];
    const float* W_hh     = (const float*)d_in[11];
    const float* b_ih     = (const float*)d_in[12];
    const float* b_hh     = (const float*)d_in[13];
    const float* Wp1      = (const float*)d_in[14];
    const float* bp1      = (const float*)d_in[15];
    const float* Wp2      = (const float*)d_in[16];
    const float* bp2      = (const float*)d_in[17];
    const float* Wv1      = (const float*)d_in[18];
    const float* bv1      = (const float*)d_in[19];
    const float* Wv2      = (const float*)d_in[20];
    const float* bv2      = (const float*)d_in[21];

    float* out = (float*)d_out;
    float* o_actions = out;
    float* o_values  = out + N_TOT;
    float* o_logp    = out + 2 * (size_t)N_TOT;
    float* o_hpi     = out + 3 * (size_t)N_TOT;
    float* o_cpi     = o_hpi + NSEQ * 256;
    float* o_hT      = o_cpi + NSEQ * 256;
    float* o_cT      = o_hT  + NSEQ * 256;

    // workspace (~89.7 MB)
    char* ws = (char*)d_ws;
    const size_t MB = 1024 * 1024;
    float* xg_c  = (float*)(ws);                 // 32 MB  (8192 x 1024)
    float* lat_c = (float*)(ws + 32 * MB);       // 32 MB  (8192 x 1024)
    float* hs_c  = (float*)(ws + 64 * MB);       //  8 MB  (8192 x 256)
    float* h1_c  = (float*)(ws + 72 * MB);       // 16 MB  (8192 x 512)
    float* Wg    = (float*)(ws + 88 * MB);       //  1 MB
    float* hstate = (float*)(ws + 89 * MB);                  // 64 KB
    float* cstate = (float*)(ws + 89 * MB + 65536);          // 64 KB
    u64*   hx     = (u64*)  (ws + 89 * MB + 131072);         // 256 KB MALL path
    u64*   hx2    = (u64*)  (ws + 89 * MB + 393216);         // 256 KB L2 fast path
    unsigned* fastState = (unsigned*)(ws + 89 * MB + 655360); // 4 B verdict flag

    const int fastflag = (ws_size >= 89 * MB + 656 * 1024) ? 1 : 0;
    u64* hx2_eff = fastflag ? hx2 : hx;
    unsigned* fs_eff = fastflag ? fastState : (unsigned*)hx;

    transpose_whh<<<256, 256, 0, stream>>>(W_hh, Wg);

    mask_kernel<<<NSEQ, 256, 0, stream>>>(starts, h_pi, c_pi, o_hpi, o_cpi);

    for (int c = 0; c < NCH; ++c) {
        const int base = c * CS;

        gemm_xg<<<dim3(8, NSEQ), 256, 0, stream>>>(features, W_ih, b_ih, b_hh,
                                                   xg_c, base);
        gemm_latent<<<dim3(8, 64), 256, 0, stream>>>(
            features, W_feat, W_emb, b_feat, b_emb, lat_c, base);

        // fused: lstm chain (bids 0..255) + policy h1p GEMM (bids 256..511)
        lstm4_h1p<<<512, 1024, 0, stream>>>(xg_c, starts, h_vf, c_vf,
                                            hstate, cstate, Wg,
                                            hs_c, o_hT, o_cT, hx, hx2_eff,
                                            fs_eff,
                                            lat_c, Wp1, bp1, h1_c,
                                            base, fastflag);

        policy_finish<<<1024, 256, 0, stream>>>(h1_c, Wp2, bp2,
                                                o_actions, o_logp, base);

        gemm_h1v<<<dim3(4, 64), 256, 0, stream>>>(lat_c, hs_c, Wv1, bv1, h1_c);
        value_finish<<<128, 256, 0, stream>>>(h1_c, Wv2, bv2, o_values, base);
    }
}